// Round 3
// baseline (248.787 us; speedup 1.0000x reference)
//
#include <hip/hip_runtime.h>

// NaiveFourierKANLayer: y = cos-features @ W0^T + sin-features @ W1^T + bias
// N=32768, INPUTDIM=64, OUTDIM=256, GRIDSIZE=32 -> GEMM M=32768, N=256, K=4096
//
// R3 changes vs R2 (gemm 109.9 us, MfmaUtil 26.5, VALUBusy 46, conflicts 0):
//  - B-tile no longer staged in LDS: B-fragments loaded straight from global
//    (Wr is 2 MB, L2-resident) into registers, double-buffered (kt+1 in
//    flight while kt computes). Each lane reads 16 B contiguous; a quad
//    covers a full 64 B line.
//  - A-tile LDS double-buffered (2 x 16 KB) -> ONE barrier per iteration,
//    and no global_load_lds vmcnt(0) drain at the barrier.
//  - x row loaded as float4 every 4 iters (rolling pair) instead of a
//    4 B/lane scatter every iter.
//  LDS instrs/block-iter: 80 -> 48. Barriers: 128 -> 64.

#define IDIM 64
#define ODIM 256
#define KDIM 4096

typedef __attribute__((ext_vector_type(8))) unsigned short ushort8_t;
typedef __bf16 bf16x8 __attribute__((ext_vector_type(8)));
typedef float floatx4 __attribute__((ext_vector_type(4)));
typedef float floatx2 __attribute__((ext_vector_type(2)));
typedef unsigned int uintx4 __attribute__((ext_vector_type(4)));

__device__ __forceinline__ unsigned short f2bf_rne(float f) {
  unsigned int u = __float_as_uint(f);
  return (unsigned short)((u + 0x7FFFu + ((u >> 16) & 1u)) >> 16);
}

// pack two fp32 -> packed bf16 pair (lo = a, hi = b)
#if __has_builtin(__builtin_amdgcn_cvt_pk_bf16_f32)
__device__ __forceinline__ unsigned int pack2bf(float a, float b) {
  auto v = __builtin_amdgcn_cvt_pk_bf16_f32(a, b);
  unsigned int r;
  __builtin_memcpy(&r, &v, 4);
  return r;
}
#else
__device__ __forceinline__ unsigned int pack2bf(float a, float b) {
  unsigned int ua = __float_as_uint(a) + 0x8000u;  // round-half-up
  unsigned int ub = __float_as_uint(b) + 0x8000u;
  return __builtin_amdgcn_perm(ub, ua, 0x07060302u);  // {hi16(b),hi16(a)}
}
#endif

// ---- weight gather+convert: fc(2,256,64,32) fp32 -> Wr(256,4096) bf16 ----
__global__ void __launch_bounds__(256) wconv(const float* __restrict__ fc,
                                             unsigned short* __restrict__ Wr) {
  int e = (blockIdx.x * 256 + threadIdx.x) << 2;  // element idx, 4 per thread
  int o = e >> 12;
  int k = e & 4095;
  int i = k >> 6;
  int c = (k >> 5) & 1;
  int g = k & 31;  // multiple of 4
  const float4 v = *(const float4*)(fc + ((size_t)c << 19) + o * 2048 + i * 32 + g);
  ushort4 r;
  r.x = f2bf_rne(v.x);
  r.y = f2bf_rne(v.y);
  r.z = f2bf_rne(v.z);
  r.w = f2bf_rne(v.w);
  *(ushort4*)(Wr + e) = r;
}

// ---- fused feature-gen + GEMM ----
__global__ void __launch_bounds__(256) fkan_gemm(const float* __restrict__ X,
                                                 const unsigned short* __restrict__ Wr,
                                                 const float* __restrict__ bias,
                                                 float* __restrict__ out) {
  // A-tile double buffer, XOR-swizzled: granule = row*8 + (chunk ^ (row&7))
  __shared__ __align__(16) unsigned short As[2][128 * 64];

  const int t = threadIdx.x;
  const int wv = t >> 6;        // wave 0..3
  const int ln = t & 63;
  const int lm = ln & 15;
  const int quad = ln >> 4;
  const int wm = wv >> 1;       // wave m-half
  const int wn = wv & 1;        // wave n-half
  const int m0 = blockIdx.y * 128;
  const int n0 = blockIdx.x * 128;

  // A-staging role: one row per thread, half of g-range per p
  const int arow = t & 127;
  const int p = t >> 7;  // 0: g=1..16, 1: g=17..32
  const float gstart = (float)(16 * p + 1);

  floatx4 acc[4][4];
#pragma unroll
  for (int a = 0; a < 4; ++a)
#pragma unroll
    for (int b = 0; b < 4; ++b)
      acc[a][b] = (floatx4){0.0f, 0.0f, 0.0f, 0.0f};

  const float* xrow = X + (size_t)(m0 + arow) * IDIM;

  // B-fragment base for this lane: col = n0 + wn*64 + nt*16 + lm,
  // frag(nt,kh) at iter kt -> bbase + nt*16*KDIM + kt*64 + kh*32
  const unsigned short* bbase =
      Wr + (size_t)(n0 + wn * 64 + lm) * KDIM + quad * 8;

  // feature generator: writes [cos g=1..32 | sin g=1..32] bf16 row into buf
  auto gen_features = [&](float xv, unsigned short* buf) {
    float u = xv * 0.15915494309189535f;  // revolutions
    float u0 = u * gstart;
    float u1 = u0 + u;
    float u2 = u + u;
    float c2 = __builtin_amdgcn_cosf(u2);
    float s2 = __builtin_amdgcn_sinf(u2);
    floatx2 C = {__builtin_amdgcn_cosf(u0), __builtin_amdgcn_cosf(u1)};
    floatx2 S = {__builtin_amdgcn_sinf(u0), __builtin_amdgcn_sinf(u1)};
    floatx2 c2v = {c2, c2};
    floatx2 s2v = {s2, s2};
    unsigned int cpk[8], spk[8];
#pragma unroll
    for (int j = 0; j < 8; ++j) {
      cpk[j] = pack2bf(C.x, C.y);
      spk[j] = pack2bf(S.x, S.y);
      floatx2 t1 = C * s2v;
      floatx2 t2 = S * s2v;
      C = __builtin_elementwise_fma(C, c2v, -t2);
      S = __builtin_elementwise_fma(S, c2v, t1);
    }
    uintx4* As4 = (uintx4*)buf;
    int sw = arow & 7;
    int gb = arow * 8;
    As4[gb + ((2 * p) ^ sw)] = (uintx4){cpk[0], cpk[1], cpk[2], cpk[3]};
    As4[gb + ((2 * p + 1) ^ sw)] = (uintx4){cpk[4], cpk[5], cpk[6], cpk[7]};
    As4[gb + ((4 + 2 * p) ^ sw)] = (uintx4){spk[0], spk[1], spk[2], spk[3]};
    As4[gb + ((5 + 2 * p) ^ sw)] = (uintx4){spk[4], spk[5], spk[6], spk[7]};
  };

  auto loadB = [&](int kt, bf16x8* Bdst) {
#pragma unroll
    for (int nt = 0; nt < 4; ++nt)
#pragma unroll
      for (int kh = 0; kh < 2; ++kh)
        Bdst[nt * 2 + kh] =
            *(const bf16x8*)(bbase + (size_t)nt * 16 * KDIM + kt * 64 + kh * 32);
  };

  // one pipelined iteration: kt current, ktn = feature/B index for next
  auto body = [&](int kt, int ktn, float xnext, bf16x8* Bcur, bf16x8* Bnxt,
                  unsigned short* bufR, unsigned short* bufW) {
    loadB(ktn, Bnxt);       // in flight across the barrier (register loads)
    __syncthreads();        // bufR writes (prev iter) now visible
    gen_features(xnext, bufW);
#pragma unroll
    for (int kh = 0; kh < 2; ++kh) {
      bf16x8 af[4];
#pragma unroll
      for (int mt = 0; mt < 4; ++mt) {
        int r = wm * 64 + mt * 16 + lm;
        int gran = r * 8 + ((kh * 4 + quad) ^ (r & 7));
        af[mt] = __builtin_bit_cast(bf16x8, ((const ushort8_t*)bufR)[gran]);
      }
#pragma unroll
      for (int mt = 0; mt < 4; ++mt)
#pragma unroll
        for (int nt = 0; nt < 4; ++nt)
          acc[mt][nt] = __builtin_amdgcn_mfma_f32_16x16x32_bf16(
              af[mt], Bcur[nt * 2 + kh], acc[mt][nt], 0, 0, 0);
    }
  };

  // ---- prologue ----
  bf16x8 Bv[2][8];
  float4 xq = *(const float4*)(xrow);  // x[0..3]
  gen_features(xq.x, As[0]);           // features(0)
  loadB(0, Bv[0]);

  // ---- main loop: 16 groups of 4 iterations ----
  for (int q = 0; q < 16; ++q) {
    float4 xqn = (q < 15) ? *(const float4*)(xrow + 4 * q + 4) : xq;
    int kt = 4 * q;
    float xl = (q < 15) ? xqn.x : xq.w;  // x for ktn of 4th body (clamped)
    int ktl = (q < 15) ? kt + 4 : 63;
    body(kt + 0, kt + 1, xq.y, Bv[0], Bv[1], As[0], As[1]);
    body(kt + 1, kt + 2, xq.z, Bv[1], Bv[0], As[1], As[0]);
    body(kt + 2, kt + 3, xq.w, Bv[0], Bv[1], As[0], As[1]);
    body(kt + 3, ktl,    xl,   Bv[1], Bv[0], As[1], As[0]);
    xq = xqn;
  }

  // ---- epilogue: C[row][col] = acc + bias, verified C/D layout ----
#pragma unroll
  for (int nt = 0; nt < 4; ++nt) {
    int col = n0 + wn * 64 + nt * 16 + lm;
    float bv = bias[col];
#pragma unroll
    for (int mt = 0; mt < 4; ++mt) {
      int rbase = m0 + wm * 64 + mt * 16 + quad * 4;
#pragma unroll
      for (int r = 0; r < 4; ++r)
        out[(size_t)(rbase + r) * ODIM + col] = acc[mt][nt][r] + bv;
    }
  }
}

extern "C" void kernel_launch(void* const* d_in, const int* in_sizes, int n_in,
                              void* d_out, int out_size, void* d_ws, size_t ws_size,
                              hipStream_t stream) {
  const float* x = (const float*)d_in[0];
  const float* fc = (const float*)d_in[1];
  const float* bias = (const float*)d_in[2];
  float* out = (float*)d_out;
  unsigned short* Wr = (unsigned short*)d_ws;  // 2 MB of workspace

  hipLaunchKernelGGL(wconv, dim3(1024), dim3(256), 0, stream, fc, Wr);
  hipLaunchKernelGGL(fkan_gemm, dim3(2, 256), dim3(256), 0, stream, x, Wr, bias, out);
}